// Round 1
// baseline (1888.293 us; speedup 1.0000x reference)
//
#include <hip/hip_runtime.h>

#define NN 100000
#define NE 1600000

// workspace layout (float offsets)
#define W1D_OFF 0
#define W1S_OFF 448
#define W2D_OFF 896
#define W2S_OFF 4992
#define AGG1_OFF 16384                 // 64KB-aligned
#define AGG2_OFF (16384 + NN * 64)

// Precombine weights: msg@Wa = xd@(Wa_top - Wa_bot) + xs@Wa_bot
__global__ __launch_bounds__(256) void prep_weights(
    const float* __restrict__ W1a, const float* __restrict__ W2a, float* __restrict__ ws)
{
    int i = blockIdx.x * blockDim.x + threadIdx.x;
    if (i < 448) {
        float top = W1a[i], bot = W1a[448 + i];
        ws[W1D_OFF + i] = top - bot;
        ws[W1S_OFF + i] = bot;
    }
    if (i < 4096) {
        float top = W2a[i], bot = W2a[4096 + i];
        ws[W2D_OFF + i] = top - bot;
        ws[W2S_OFF + i] = bot;
    }
}

// Layer 1: thread-per-edge MLP (7-ch input), LDS transpose, coalesced atomicMax.
__global__ __launch_bounds__(256, 2) void edge_layer1(
    const float* __restrict__ x,
    const int* __restrict__ src, const int* __restrict__ dst,
    const float* __restrict__ Wd, const float* __restrict__ Ws,
    const float* __restrict__ ba, const float* __restrict__ Wb,
    const float* __restrict__ bb,
    unsigned int* __restrict__ agg)
{
    __shared__ float hbuf[256 * 64];   // rotation-swizzled, conflict-free
    const int tid = threadIdx.x;
    const int e = blockIdx.x * 256 + tid;
    const int s = src[e];
    const int d = dst[e];

    float xd[7], xs[7];
#pragma unroll
    for (int k = 0; k < 7; ++k) { xd[k] = x[d * 7 + k]; xs[k] = x[s * 7 + k]; }

    float t[64];
#pragma unroll
    for (int c = 0; c < 64; ++c) t[c] = ba[c];
#pragma unroll
    for (int k = 0; k < 7; ++k) {
#pragma unroll
        for (int c = 0; c < 64; ++c) t[c] = fmaf(xd[k], Wd[k * 64 + c], t[c]);
#pragma unroll
        for (int c = 0; c < 64; ++c) t[c] = fmaf(xs[k], Ws[k * 64 + c], t[c]);
    }
#pragma unroll
    for (int c = 0; c < 64; ++c) t[c] = fmaxf(t[c], 0.0f);

#pragma unroll
    for (int half = 0; half < 2; ++half) {
        float h[32];
#pragma unroll
        for (int c = 0; c < 32; ++c) h[c] = bb[half * 32 + c];
#pragma unroll
        for (int j = 0; j < 64; ++j) {
#pragma unroll
            for (int c = 0; c < 32; ++c)
                h[c] = fmaf(t[j], Wb[j * 64 + half * 32 + c], h[c]);
        }
#pragma unroll
        for (int c = 0; c < 32; ++c) {
            int cc = half * 32 + c;
            // clamp at 0 here: max(0, max_e h) == max over edges of max(h,0)
            hbuf[tid * 64 + ((cc + tid) & 63)] = fmaxf(h[c], 0.0f);
        }
    }
    __syncthreads();

    // wave-per-64-edges, lane = channel -> 256B coalesced atomics
    const int wv = tid >> 6, lane = tid & 63;
    const int ebase = blockIdx.x * 256 + wv * 64;
#pragma unroll 4
    for (int i = 0; i < 64; ++i) {
        int ee = wv * 64 + i;
        float v = hbuf[ee * 64 + ((lane + ee) & 63)];
        int dd = dst[ebase + i];                    // wave-uniform -> s_load
        atomicMax(&agg[dd * 64 + lane], __float_as_uint(v));
    }
}

// Layer 2: thread-per-edge MLP (64-ch input gathered from h1).
__global__ __launch_bounds__(256, 2) void edge_layer2(
    const float* __restrict__ h1,
    const int* __restrict__ src, const int* __restrict__ dst,
    const float* __restrict__ Wd, const float* __restrict__ Ws,
    const float* __restrict__ ba, const float* __restrict__ Wb,
    const float* __restrict__ bb,
    unsigned int* __restrict__ agg)
{
    __shared__ float hbuf[256 * 64];
    const int tid = threadIdx.x;
    const int e = blockIdx.x * 256 + tid;
    const int s = src[e];
    const int d = dst[e];

    const float4* pd = (const float4*)(h1 + (size_t)d * 64);
    const float4* ps = (const float4*)(h1 + (size_t)s * 64);

    float t[64];
#pragma unroll
    for (int c = 0; c < 64; ++c) t[c] = ba[c];

#pragma unroll 1
    for (int q = 0; q < 4; ++q) {   // chunk k-dim: bounds register pressure + code size
        float hd[16], hs[16];
#pragma unroll
        for (int m = 0; m < 4; ++m) {
            float4 a = pd[q * 4 + m];
            hd[m * 4 + 0] = a.x; hd[m * 4 + 1] = a.y; hd[m * 4 + 2] = a.z; hd[m * 4 + 3] = a.w;
            float4 b = ps[q * 4 + m];
            hs[m * 4 + 0] = b.x; hs[m * 4 + 1] = b.y; hs[m * 4 + 2] = b.z; hs[m * 4 + 3] = b.w;
        }
        const float* Wdq = Wd + q * 16 * 64;
        const float* Wsq = Ws + q * 16 * 64;
#pragma unroll
        for (int kk = 0; kk < 16; ++kk) {
#pragma unroll
            for (int c = 0; c < 64; ++c) t[c] = fmaf(hd[kk], Wdq[kk * 64 + c], t[c]);
#pragma unroll
            for (int c = 0; c < 64; ++c) t[c] = fmaf(hs[kk], Wsq[kk * 64 + c], t[c]);
        }
    }
#pragma unroll
    for (int c = 0; c < 64; ++c) t[c] = fmaxf(t[c], 0.0f);

#pragma unroll
    for (int half = 0; half < 2; ++half) {
        float h[32];
#pragma unroll
        for (int c = 0; c < 32; ++c) h[c] = bb[half * 32 + c];
#pragma unroll
        for (int j = 0; j < 64; ++j) {
#pragma unroll
            for (int c = 0; c < 32; ++c)
                h[c] = fmaf(t[j], Wb[j * 64 + half * 32 + c], h[c]);
        }
#pragma unroll
        for (int c = 0; c < 32; ++c) {
            int cc = half * 32 + c;
            hbuf[tid * 64 + ((cc + tid) & 63)] = fmaxf(h[c], 0.0f);
        }
    }
    __syncthreads();

    const int wv = tid >> 6, lane = tid & 63;
    const int ebase = blockIdx.x * 256 + wv * 64;
#pragma unroll 4
    for (int i = 0; i < 64; ++i) {
        int ee = wv * 64 + i;
        float v = hbuf[ee * 64 + ((lane + ee) & 63)];
        int dd = dst[ebase + i];
        atomicMax(&agg[dd * 64 + lane], __float_as_uint(v));
    }
}

// out[i] = h2[i,:] @ Wl + bl
__global__ __launch_bounds__(256) void final_linear(
    const float* __restrict__ h2, const float* __restrict__ Wl,
    const float* __restrict__ bl, float* __restrict__ out)
{
    int i = blockIdx.x * 256 + threadIdx.x;
    if (i >= NN) return;
    const float4* row = (const float4*)(h2 + (size_t)i * 64);
    float acc = bl[0];
#pragma unroll
    for (int q = 0; q < 16; ++q) {
        float4 v = row[q];
        acc = fmaf(v.x, Wl[q * 4 + 0], acc);
        acc = fmaf(v.y, Wl[q * 4 + 1], acc);
        acc = fmaf(v.z, Wl[q * 4 + 2], acc);
        acc = fmaf(v.w, Wl[q * 4 + 3], acc);
    }
    out[i] = acc;
}

extern "C" void kernel_launch(void* const* d_in, const int* in_sizes, int n_in,
                              void* d_out, int out_size, void* d_ws, size_t ws_size,
                              hipStream_t stream)
{
    const float* x   = (const float*)d_in[0];
    const int*   ei  = (const int*)d_in[1];
    const float* W1a = (const float*)d_in[2];
    const float* b1a = (const float*)d_in[3];
    const float* W1b = (const float*)d_in[4];
    const float* b1b = (const float*)d_in[5];
    const float* W2a = (const float*)d_in[6];
    const float* b2a = (const float*)d_in[7];
    const float* W2b = (const float*)d_in[8];
    const float* b2b = (const float*)d_in[9];
    const float* Wl  = (const float*)d_in[10];
    const float* bl  = (const float*)d_in[11];

    float* ws = (float*)d_ws;
    unsigned int* agg1 = (unsigned int*)(ws + AGG1_OFF);
    unsigned int* agg2 = (unsigned int*)(ws + AGG2_OFF);

    // zero both aggregation buffers (contiguous); ws is re-poisoned every call
    hipMemsetAsync(agg1, 0, (size_t)2 * NN * 64 * sizeof(float), stream);

    prep_weights<<<16, 256, 0, stream>>>(W1a, W2a, ws);
    edge_layer1<<<NE / 256, 256, 0, stream>>>(x, ei, ei + NE,
                                              ws + W1D_OFF, ws + W1S_OFF,
                                              b1a, W1b, b1b, agg1);
    edge_layer2<<<NE / 256, 256, 0, stream>>>((const float*)agg1, ei, ei + NE,
                                              ws + W2D_OFF, ws + W2S_OFF,
                                              b2a, W2b, b2b, agg2);
    final_linear<<<(NN + 255) / 256, 256, 0, stream>>>((const float*)agg2, Wl, bl,
                                                       (float*)d_out);
}

// Round 2
// 949.019 us; speedup vs baseline: 1.9897x; 1.9897x over previous
//
#include <hip/hip_runtime.h>

#define NN 100000
#define NE 1600000
#define N64 (NN * 64)

// ---- workspace layout (float offsets) ----
#define W1D_OFF 0
#define W1S_OFF 448
#define W2D_OFF 896
#define W2S_OFF 4992
#define A_OFF   16384
#define B_OFF   (A_OFF + N64)
#define AGG_OFF (B_OFF + N64)
#define INT_OFF (AGG_OFF + N64)     // int region starts here (float offset)
// int offsets within the int region:
#define CNT_I   0                    // counts   [100352]
#define CUR_I   100352               // cursor   [100352]
#define PART_I  200704               // partials [512]
#define BASE_I  201216               // base     [512]
#define SSRC_I  201728               // sorted src [NE]
#define SDST_I  (201728 + NE)        // sorted dst [NE]

// Precombine weights: msg@Wa = xd@(Wa_top - Wa_bot) + xs@Wa_bot
__global__ __launch_bounds__(256) void prep_weights(
    const float* __restrict__ W1a, const float* __restrict__ W2a, float* __restrict__ ws)
{
    int i = blockIdx.x * blockDim.x + threadIdx.x;
    if (i < 448) {
        float top = W1a[i], bot = W1a[448 + i];
        ws[W1D_OFF + i] = top - bot;
        ws[W1S_OFF + i] = bot;
    }
    if (i < 4096) {
        float top = W2a[i], bot = W2a[4096 + i];
        ws[W2D_OFF + i] = top - bot;
        ws[W2S_OFF + i] = bot;
    }
}

// A[i] = x_i @ Wd + ba ; B[i] = x_i @ Ws   (7-ch input)
__global__ __launch_bounds__(256) void node_mlp1(
    const float* __restrict__ x, const float* __restrict__ Wd,
    const float* __restrict__ Ws, const float* __restrict__ ba,
    float* __restrict__ A, float* __restrict__ Bv)
{
    int i = blockIdx.x * 256 + threadIdx.x;
    if (i >= NN) return;
    float xv[7];
#pragma unroll
    for (int k = 0; k < 7; ++k) xv[k] = x[i * 7 + k];
    float4* pa = (float4*)(A + (size_t)i * 64);
    float4* pb = (float4*)(Bv + (size_t)i * 64);
#pragma unroll
    for (int half = 0; half < 2; ++half) {
        float acc[32];
#pragma unroll
        for (int c = 0; c < 32; ++c) acc[c] = ba[half * 32 + c];
#pragma unroll
        for (int k = 0; k < 7; ++k)
#pragma unroll
            for (int c = 0; c < 32; ++c)
                acc[c] = fmaf(xv[k], Wd[k * 64 + half * 32 + c], acc[c]);
#pragma unroll
        for (int q = 0; q < 8; ++q)
            pa[half * 8 + q] = make_float4(acc[q*4], acc[q*4+1], acc[q*4+2], acc[q*4+3]);
#pragma unroll
        for (int c = 0; c < 32; ++c) acc[c] = 0.0f;
#pragma unroll
        for (int k = 0; k < 7; ++k)
#pragma unroll
            for (int c = 0; c < 32; ++c)
                acc[c] = fmaf(xv[k], Ws[k * 64 + half * 32 + c], acc[c]);
#pragma unroll
        for (int q = 0; q < 8; ++q)
            pb[half * 8 + q] = make_float4(acc[q*4], acc[q*4+1], acc[q*4+2], acc[q*4+3]);
    }
}

// A[i] = g_i @ Wd + ba2 ; B[i] = g_i @ Ws   (64-ch input, g = layer-1 output)
__global__ __launch_bounds__(256) void node_mlp2(
    const float* __restrict__ g, const float* __restrict__ Wd,
    const float* __restrict__ Ws, const float* __restrict__ ba2,
    float* __restrict__ A, float* __restrict__ Bv)
{
    int i = blockIdx.x * 256 + threadIdx.x;
    if (i >= NN) return;
    float gv[64];
    const float4* pg = (const float4*)(g + (size_t)i * 64);
#pragma unroll
    for (int q = 0; q < 16; ++q) {
        float4 v = pg[q];
        gv[q*4+0] = v.x; gv[q*4+1] = v.y; gv[q*4+2] = v.z; gv[q*4+3] = v.w;
    }
    float4* pa = (float4*)(A + (size_t)i * 64);
    float4* pb = (float4*)(Bv + (size_t)i * 64);
#pragma unroll
    for (int half = 0; half < 2; ++half) {
        float acc[32];
#pragma unroll
        for (int c = 0; c < 32; ++c) acc[c] = ba2[half * 32 + c];
#pragma unroll
        for (int j = 0; j < 64; ++j)
#pragma unroll
            for (int c = 0; c < 32; ++c)
                acc[c] = fmaf(gv[j], Wd[j * 64 + half * 32 + c], acc[c]);
#pragma unroll
        for (int q = 0; q < 8; ++q)
            pa[half * 8 + q] = make_float4(acc[q*4], acc[q*4+1], acc[q*4+2], acc[q*4+3]);
#pragma unroll
        for (int c = 0; c < 32; ++c) acc[c] = 0.0f;
#pragma unroll
        for (int j = 0; j < 64; ++j)
#pragma unroll
            for (int c = 0; c < 32; ++c)
                acc[c] = fmaf(gv[j], Ws[j * 64 + half * 32 + c], acc[c]);
#pragma unroll
        for (int q = 0; q < 8; ++q)
            pb[half * 8 + q] = make_float4(acc[q*4], acc[q*4+1], acc[q*4+2], acc[q*4+3]);
    }
}

// ---- counting sort of edges by dst ----
__global__ __launch_bounds__(256) void k_hist(const int* __restrict__ dst, int* __restrict__ counts)
{
    int e = blockIdx.x * 256 + threadIdx.x;
    if (e < NE) atomicAdd(&counts[dst[e]], 1);
}

// block-level exclusive scan (256-wide chunks)
__global__ __launch_bounds__(256) void k_scanA(
    const int* __restrict__ counts, int* __restrict__ cursor, int* __restrict__ partials)
{
    __shared__ int sh[256];
    int t = threadIdx.x, i = blockIdx.x * 256 + t;
    int c = counts[i];                     // padded region is zeroed
    sh[t] = c; __syncthreads();
#pragma unroll
    for (int off = 1; off < 256; off <<= 1) {
        int v = (t >= off) ? sh[t - off] : 0;
        __syncthreads();
        sh[t] += v;
        __syncthreads();
    }
    cursor[i] = sh[t] - c;                 // exclusive within chunk
    if (t == 255) partials[blockIdx.x] = sh[t];
}

__global__ __launch_bounds__(512) void k_scanB(const int* __restrict__ partials, int* __restrict__ base)
{
    __shared__ int sh[512];
    int t = threadIdx.x;
    int c = (t < 392) ? partials[t] : 0;
    sh[t] = c; __syncthreads();
#pragma unroll
    for (int off = 1; off < 512; off <<= 1) {
        int v = (t >= off) ? sh[t - off] : 0;
        __syncthreads();
        sh[t] += v;
        __syncthreads();
    }
    if (t < 392) base[t] = sh[t] - c;      // exclusive chunk bases
}

__global__ __launch_bounds__(256) void k_scatter(
    const int* __restrict__ src, const int* __restrict__ dst,
    int* __restrict__ cursor, const int* __restrict__ base,
    int* __restrict__ ssrc, int* __restrict__ sdst)
{
    int e = blockIdx.x * 256 + threadIdx.x;
    if (e >= NE) return;
    int dd = dst[e];
    int pos = atomicAdd(&cursor[dd], 1) + base[dd >> 8];
    ssrc[pos] = src[e];
    sdst[pos] = dd;
}

// Per-edge: t=relu(A[dst]+B[src]); h=relu(t@Wb+bb); segmented max into agg.
__global__ __launch_bounds__(256, 2) void edge_layer(
    const float* __restrict__ A, const float* __restrict__ Bv,
    const int* __restrict__ ssrc, const int* __restrict__ sdst,
    const float* __restrict__ Wb, const float* __restrict__ bb,
    unsigned int* __restrict__ agg)
{
    __shared__ float hbuf[256 * 64];       // rotation-swizzled, conflict-free
    const int tid = threadIdx.x;
    const int e = blockIdx.x * 256 + tid;
    const int s = ssrc[e];
    const int d = sdst[e];

    const float4* pa = (const float4*)(A + (size_t)d * 64);
    const float4* pb = (const float4*)(Bv + (size_t)s * 64);
    float t[64];
#pragma unroll
    for (int q = 0; q < 16; ++q) {
        float4 a = pa[q], b = pb[q];
        t[q*4+0] = fmaxf(a.x + b.x, 0.0f);
        t[q*4+1] = fmaxf(a.y + b.y, 0.0f);
        t[q*4+2] = fmaxf(a.z + b.z, 0.0f);
        t[q*4+3] = fmaxf(a.w + b.w, 0.0f);
    }

#pragma unroll
    for (int half = 0; half < 2; ++half) {
        float h[32];
#pragma unroll
        for (int c = 0; c < 32; ++c) h[c] = bb[half * 32 + c];
#pragma unroll
        for (int j = 0; j < 64; ++j)
#pragma unroll
            for (int c = 0; c < 32; ++c)
                h[c] = fmaf(t[j], Wb[j * 64 + half * 32 + c], h[c]);
#pragma unroll
        for (int c = 0; c < 32; ++c) {
            int cc = half * 32 + c;
            // clamp at 0: max(0, max_e h) == max over edges of max(h,0)
            hbuf[tid * 64 + ((cc + tid) & 63)] = fmaxf(h[c], 0.0f);
        }
    }
    __syncthreads();

    // segmented aggregation: edges are dst-sorted -> runs share dst.
    const int wv = tid >> 6, lane = tid & 63;
    const int ebase = blockIdx.x * 256 + wv * 64;
    int dval = sdst[ebase + lane];                          // this wave's 64 dsts
    int dprev = __builtin_amdgcn_readfirstlane(dval);
    float run = 0.0f;
#pragma unroll
    for (int i = 0; i < 64; ++i) {
        int ee = wv * 64 + i;
        float v = hbuf[ee * 64 + ((lane + ee) & 63)];
        int dd = __builtin_amdgcn_readlane(dval, i);        // wave-uniform scalar
        if (dd != dprev) {                                   // uniform branch
            atomicMax(&agg[(size_t)dprev * 64 + lane], __float_as_uint(run));
            run = 0.0f;
            dprev = dd;
        }
        run = fmaxf(run, v);
    }
    atomicMax(&agg[(size_t)dprev * 64 + lane], __float_as_uint(run));
}

// out[i] = h2[i,:] @ Wl + bl
__global__ __launch_bounds__(256) void final_linear(
    const float* __restrict__ h2, const float* __restrict__ Wl,
    const float* __restrict__ bl, float* __restrict__ out)
{
    int i = blockIdx.x * 256 + threadIdx.x;
    if (i >= NN) return;
    const float4* row = (const float4*)(h2 + (size_t)i * 64);
    float acc = bl[0];
#pragma unroll
    for (int q = 0; q < 16; ++q) {
        float4 v = row[q];
        acc = fmaf(v.x, Wl[q * 4 + 0], acc);
        acc = fmaf(v.y, Wl[q * 4 + 1], acc);
        acc = fmaf(v.z, Wl[q * 4 + 2], acc);
        acc = fmaf(v.w, Wl[q * 4 + 3], acc);
    }
    out[i] = acc;
}

extern "C" void kernel_launch(void* const* d_in, const int* in_sizes, int n_in,
                              void* d_out, int out_size, void* d_ws, size_t ws_size,
                              hipStream_t stream)
{
    const float* x   = (const float*)d_in[0];
    const int*   ei  = (const int*)d_in[1];
    const float* W1a = (const float*)d_in[2];
    const float* b1a = (const float*)d_in[3];
    const float* W1b = (const float*)d_in[4];
    const float* b1b = (const float*)d_in[5];
    const float* W2a = (const float*)d_in[6];
    const float* b2a = (const float*)d_in[7];
    const float* W2b = (const float*)d_in[8];
    const float* b2b = (const float*)d_in[9];
    const float* Wl  = (const float*)d_in[10];
    const float* bl  = (const float*)d_in[11];

    const int* src = ei;
    const int* dst = ei + NE;

    float* ws = (float*)d_ws;
    float* A    = ws + A_OFF;
    float* B    = ws + B_OFF;
    unsigned int* AGG = (unsigned int*)(ws + AGG_OFF);
    int* ib = (int*)(ws + INT_OFF);
    int* counts   = ib + CNT_I;
    int* cursor   = ib + CUR_I;
    int* partials = ib + PART_I;
    int* base     = ib + BASE_I;
    int* ssrc     = ib + SSRC_I;
    int* sdst     = ib + SDST_I;

    // zero histogram (incl. padding) and layer-1 agg buffer
    hipMemsetAsync(counts, 0, 100352 * sizeof(int), stream);
    hipMemsetAsync(AGG, 0, (size_t)N64 * sizeof(float), stream);

    prep_weights<<<16, 256, 0, stream>>>(W1a, W2a, ws);
    node_mlp1<<<391, 256, 0, stream>>>(x, ws + W1D_OFF, ws + W1S_OFF, b1a, A, B);

    // counting sort by dst
    k_hist   <<<NE / 256, 256, 0, stream>>>(dst, counts);
    k_scanA  <<<392, 256, 0, stream>>>(counts, cursor, partials);
    k_scanB  <<<1, 512, 0, stream>>>(partials, base);
    k_scatter<<<NE / 256, 256, 0, stream>>>(src, dst, cursor, base, ssrc, sdst);

    // layer 1 edges
    edge_layer<<<NE / 256, 256, 0, stream>>>(A, B, ssrc, sdst, W1b, b1b, AGG);

    // layer 2 node precompute (reads AGG as float), then re-zero AGG and run edges
    node_mlp2<<<391, 256, 0, stream>>>((const float*)AGG, ws + W2D_OFF, ws + W2S_OFF, b2a, A, B);
    hipMemsetAsync(AGG, 0, (size_t)N64 * sizeof(float), stream);
    edge_layer<<<NE / 256, 256, 0, stream>>>(A, B, ssrc, sdst, W2b, b2b, AGG);

    final_linear<<<391, 256, 0, stream>>>((const float*)AGG, Wl, bl, (float*)d_out);
}

// Round 3
// 675.055 us; speedup vs baseline: 2.7972x; 1.4058x over previous
//
#include <hip/hip_runtime.h>

#define NN 100000
#define NE 1600000
#define N64 (NN * 64)

typedef __attribute__((ext_vector_type(8))) short bf16x8;
typedef __attribute__((ext_vector_type(4))) float fx4;

// ---- workspace layout (float/dword offsets) ----
#define W1D_OFF 0
#define W1S_OFF 448
#define W2D_OFF 896
#define W2S_OFF 4992
#define WB1F_OFF 9216                 // packed Wb frags layer1: 4096 dwords
#define WB2F_OFF 13312                // layer2: 4096 dwords
#define A_OFF   32768
#define B_OFF   (A_OFF + N64)
#define AGG_OFF (B_OFF + N64)
#define INT_OFF (AGG_OFF + N64)
#define CNT_I   0
#define CUR_I   100352
#define PART_I  200704
#define BASE_I  201216
#define SSRC_I  201728
#define SDST_I  (201728 + NE)

// Precombine weights: msg@Wa = xd@(Wa_top - Wa_bot) + xs@Wa_bot
__global__ __launch_bounds__(256) void prep_weights(
    const float* __restrict__ W1a, const float* __restrict__ W2a, float* __restrict__ ws)
{
    int i = blockIdx.x * blockDim.x + threadIdx.x;
    if (i < 448) {
        float top = W1a[i], bot = W1a[448 + i];
        ws[W1D_OFF + i] = top - bot;
        ws[W1S_OFF + i] = bot;
    }
    if (i < 4096) {
        float top = W2a[i], bot = W2a[4096 + i];
        ws[W2D_OFF + i] = top - bot;
        ws[W2S_OFF + i] = bot;
    }
}

// Build MFMA B-operand fragments of Wb (hi/lo truncation split), pre-swizzled:
// layout [mat(2)][ks(2)][nt(4)][lane(64)][4 dwords]; B[k][n]=Wb[k*64+n],
// lane supplies k=(lane>>4)*8+j+32*ks, n=(lane&15)+16*nt, j=0..7 packed 2/dword.
__global__ __launch_bounds__(256) void prep_frags(
    const float* __restrict__ W1b, const float* __restrict__ W2b, float* __restrict__ ws)
{
    int t = blockIdx.x * 256 + threadIdx.x;
    if (t >= 2048) return;
    int layer = t >> 10;
    int r = t & 1023;                       // r = mat*512 + ks*256 + nt*64 + lane
    int ks = (r >> 8) & 1, nt = (r >> 6) & 3, lane = r & 63, mat = r >> 9;
    const float* Wb = layer ? W2b : W1b;
    int* out = (int*)(ws + (layer ? WB2F_OFF : WB1F_OFF));
    int quad = lane >> 4, c = lane & 15, n = nt * 16 + c;
    unsigned dw[4];
#pragma unroll
    for (int d = 0; d < 4; ++d) {
        unsigned v[2];
#pragma unroll
        for (int e = 0; e < 2; ++e) {
            int k = quad * 8 + d * 2 + e + 32 * ks;
            float w = Wb[k * 64 + n];
            unsigned u = __float_as_uint(w);
            if (mat == 0) v[e] = u >> 16;                       // hi = trunc
            else {
                float lo = w - __uint_as_float(u & 0xFFFF0000u); // exact residual
                v[e] = __float_as_uint(lo) >> 16;                // lo = trunc
            }
        }
        dw[d] = (v[1] << 16) | v[0];
    }
    ((int4*)out)[r] = make_int4((int)dw[0], (int)dw[1], (int)dw[2], (int)dw[3]);
}

// A[i] = x_i @ Wd + ba ; B[i] = x_i @ Ws   (7-ch input)
__global__ __launch_bounds__(256) void node_mlp1(
    const float* __restrict__ x, const float* __restrict__ Wd,
    const float* __restrict__ Ws, const float* __restrict__ ba,
    float* __restrict__ A, float* __restrict__ Bv)
{
    int i = blockIdx.x * 256 + threadIdx.x;
    if (i >= NN) return;
    float xv[7];
#pragma unroll
    for (int k = 0; k < 7; ++k) xv[k] = x[i * 7 + k];
    float4* pa = (float4*)(A + (size_t)i * 64);
    float4* pb = (float4*)(Bv + (size_t)i * 64);
#pragma unroll
    for (int half = 0; half < 2; ++half) {
        float acc[32];
#pragma unroll
        for (int c = 0; c < 32; ++c) acc[c] = ba[half * 32 + c];
#pragma unroll
        for (int k = 0; k < 7; ++k)
#pragma unroll
            for (int c = 0; c < 32; ++c)
                acc[c] = fmaf(xv[k], Wd[k * 64 + half * 32 + c], acc[c]);
#pragma unroll
        for (int q = 0; q < 8; ++q)
            pa[half * 8 + q] = make_float4(acc[q*4], acc[q*4+1], acc[q*4+2], acc[q*4+3]);
#pragma unroll
        for (int c = 0; c < 32; ++c) acc[c] = 0.0f;
#pragma unroll
        for (int k = 0; k < 7; ++k)
#pragma unroll
            for (int c = 0; c < 32; ++c)
                acc[c] = fmaf(xv[k], Ws[k * 64 + half * 32 + c], acc[c]);
#pragma unroll
        for (int q = 0; q < 8; ++q)
            pb[half * 8 + q] = make_float4(acc[q*4], acc[q*4+1], acc[q*4+2], acc[q*4+3]);
    }
}

// A[i] = g_i @ Wd + ba2 ; B[i] = g_i @ Ws ; then zero g row (re-arm AGG for layer 2)
__global__ __launch_bounds__(256) void node_mlp2(
    float* __restrict__ g, const float* __restrict__ Wd,
    const float* __restrict__ Ws, const float* __restrict__ ba2,
    float* __restrict__ A, float* __restrict__ Bv)
{
    int i = blockIdx.x * 256 + threadIdx.x;
    if (i >= NN) return;
    float gv[64];
    float4* pg = (float4*)(g + (size_t)i * 64);
#pragma unroll
    for (int q = 0; q < 16; ++q) {
        float4 v = pg[q];
        gv[q*4+0] = v.x; gv[q*4+1] = v.y; gv[q*4+2] = v.z; gv[q*4+3] = v.w;
    }
#pragma unroll
    for (int q = 0; q < 16; ++q) pg[q] = make_float4(0.f, 0.f, 0.f, 0.f);
    float4* pa = (float4*)(A + (size_t)i * 64);
    float4* pb = (float4*)(Bv + (size_t)i * 64);
#pragma unroll
    for (int half = 0; half < 2; ++half) {
        float acc[32];
#pragma unroll
        for (int c = 0; c < 32; ++c) acc[c] = ba2[half * 32 + c];
#pragma unroll
        for (int j = 0; j < 64; ++j)
#pragma unroll
            for (int c = 0; c < 32; ++c)
                acc[c] = fmaf(gv[j], Wd[j * 64 + half * 32 + c], acc[c]);
#pragma unroll
        for (int q = 0; q < 8; ++q)
            pa[half * 8 + q] = make_float4(acc[q*4], acc[q*4+1], acc[q*4+2], acc[q*4+3]);
#pragma unroll
        for (int c = 0; c < 32; ++c) acc[c] = 0.0f;
#pragma unroll
        for (int j = 0; j < 64; ++j)
#pragma unroll
            for (int c = 0; c < 32; ++c)
                acc[c] = fmaf(gv[j], Ws[j * 64 + half * 32 + c], acc[c]);
#pragma unroll
        for (int q = 0; q < 8; ++q)
            pb[half * 8 + q] = make_float4(acc[q*4], acc[q*4+1], acc[q*4+2], acc[q*4+3]);
    }
}

// ---- counting sort of edges by dst ----
__global__ __launch_bounds__(256) void k_hist(const int* __restrict__ dst, int* __restrict__ counts)
{
    int e = blockIdx.x * 256 + threadIdx.x;
    if (e < NE) atomicAdd(&counts[dst[e]], 1);
}

__global__ __launch_bounds__(256) void k_scanA(
    const int* __restrict__ counts, int* __restrict__ cursor, int* __restrict__ partials)
{
    __shared__ int sh[256];
    int t = threadIdx.x, i = blockIdx.x * 256 + t;
    int c = counts[i];
    sh[t] = c; __syncthreads();
#pragma unroll
    for (int off = 1; off < 256; off <<= 1) {
        int v = (t >= off) ? sh[t - off] : 0;
        __syncthreads();
        sh[t] += v;
        __syncthreads();
    }
    cursor[i] = sh[t] - c;
    if (t == 255) partials[blockIdx.x] = sh[t];
}

__global__ __launch_bounds__(512) void k_scanB(const int* __restrict__ partials, int* __restrict__ base)
{
    __shared__ int sh[512];
    int t = threadIdx.x;
    int c = (t < 392) ? partials[t] : 0;
    sh[t] = c; __syncthreads();
#pragma unroll
    for (int off = 1; off < 512; off <<= 1) {
        int v = (t >= off) ? sh[t - off] : 0;
        __syncthreads();
        sh[t] += v;
        __syncthreads();
    }
    if (t < 392) base[t] = sh[t] - c;
}

__global__ __launch_bounds__(256) void k_scatter(
    const int* __restrict__ src, const int* __restrict__ dst,
    int* __restrict__ cursor, const int* __restrict__ base,
    int* __restrict__ ssrc, int* __restrict__ sdst)
{
    int e = blockIdx.x * 256 + threadIdx.x;
    if (e >= NE) return;
    int dd = dst[e];
    int pos = atomicAdd(&cursor[dd], 1) + base[dd >> 8];
    ssrc[pos] = src[e];
    sdst[pos] = dd;
}

union FragU { int i[4]; bf16x8 f; };

// MFMA edge layer: per wave 64 edges. t=relu(A[d]+B[s]) split to bf16 hi/lo,
// staged in per-wave LDS; h = t@Wb via 3-pass split-bf16 MFMA (16x16x32);
// epilogue bias+relu -> LDS transpose -> segmented atomicMax. No __syncthreads.
__global__ __launch_bounds__(256, 2) void edge_layer_mfma(
    const float* __restrict__ A, const float* __restrict__ Bv,
    const int* __restrict__ ssrc, const int* __restrict__ sdst,
    const int* __restrict__ wbf, const float* __restrict__ bb,
    unsigned int* __restrict__ agg)
{
    __shared__ int lds[4][4096];             // 16 KB per wave, 64 KB total
    const int tid = threadIdx.x;
    const int wv = tid >> 6, lane = tid & 63;
    int* my = lds[wv];
    const int quad = lane >> 4, c15 = lane & 15;

    const int base = (blockIdx.x * 4 + wv) * 64;
    const int s = ssrc[base + lane];
    const int d = sdst[base + lane];

    // B-operand fragments (L1-hot, coalesced int4)
    bf16x8 bfr[2][2][4];
#pragma unroll
    for (int mat = 0; mat < 2; ++mat)
#pragma unroll
        for (int ks = 0; ks < 2; ++ks)
#pragma unroll
            for (int nt = 0; nt < 4; ++nt) {
                int4 v = ((const int4*)(wbf + ((((mat*2+ks)*4+nt)*64 + lane) * 4)))[0];
                FragU u; u.i[0]=v.x; u.i[1]=v.y; u.i[2]=v.z; u.i[3]=v.w;
                bfr[mat][ks][nt] = u.f;
            }

    // gather both 64-ch rows, t = relu(A[d]+B[s])
    const float4* pa = (const float4*)(A + (size_t)d * 64);
    const float4* pb = (const float4*)(Bv + (size_t)s * 64);
    float tv[64];
#pragma unroll
    for (int q = 0; q < 16; ++q) {
        float4 a = pa[q], b = pb[q];
        tv[q*4+0] = fmaxf(a.x + b.x, 0.f);
        tv[q*4+1] = fmaxf(a.y + b.y, 0.f);
        tv[q*4+2] = fmaxf(a.z + b.z, 0.f);
        tv[q*4+3] = fmaxf(a.w + b.w, 0.f);
    }

    fx4 acc[4][4];
#pragma unroll
    for (int mt = 0; mt < 4; ++mt)
#pragma unroll
        for (int nt = 0; nt < 4; ++nt)
            acc[mt][nt] = (fx4){0.f, 0.f, 0.f, 0.f};

    // K chunks of 32: stage hi/lo (stride 17 dwords: 2-way max bank aliasing)
#pragma unroll
    for (int ks = 0; ks < 2; ++ks) {
        const int rh = lane * 17, rl = 1088 + lane * 17;
#pragma unroll
        for (int dw = 0; dw < 16; ++dw) {
            float f0 = tv[ks*32 + dw*2], f1 = tv[ks*32 + dw*2 + 1];
            unsigned u0 = __float_as_uint(f0), u1 = __float_as_uint(f1);
            my[rh + dw] = (int)((u1 & 0xFFFF0000u) | (u0 >> 16));
            float l0 = f0 - __uint_as_float(u0 & 0xFFFF0000u);
            float l1 = f1 - __uint_as_float(u1 & 0xFFFF0000u);
            my[rl + dw] = (int)((__float_as_uint(l1) & 0xFFFF0000u) |
                                (__float_as_uint(l0) >> 16));
        }
#pragma unroll
        for (int mt = 0; mt < 4; ++mt) {
            int row = mt * 16 + c15;
            int oh = row * 17 + quad * 4;
            int ol = 1088 + row * 17 + quad * 4;
            FragU uh, ul;
#pragma unroll
            for (int d2 = 0; d2 < 4; ++d2) { uh.i[d2] = my[oh + d2]; ul.i[d2] = my[ol + d2]; }
            bf16x8 fah = uh.f, fal = ul.f;
#pragma unroll
            for (int nt = 0; nt < 4; ++nt) {
                acc[mt][nt] = __builtin_amdgcn_mfma_f32_16x16x32_bf16(fah, bfr[0][ks][nt], acc[mt][nt], 0, 0, 0);
                acc[mt][nt] = __builtin_amdgcn_mfma_f32_16x16x32_bf16(fah, bfr[1][ks][nt], acc[mt][nt], 0, 0, 0);
                acc[mt][nt] = __builtin_amdgcn_mfma_f32_16x16x32_bf16(fal, bfr[0][ks][nt], acc[mt][nt], 0, 0, 0);
            }
        }
    }

    // epilogue: bias + relu, write rotation-swizzled [edge][ch] into LDS
    float bbv[4];
#pragma unroll
    for (int nt = 0; nt < 4; ++nt) bbv[nt] = bb[nt * 16 + c15];
#pragma unroll
    for (int mt = 0; mt < 4; ++mt)
#pragma unroll
        for (int nt = 0; nt < 4; ++nt)
#pragma unroll
            for (int r = 0; r < 4; ++r) {
                int edge = mt * 16 + quad * 4 + r;
                int ch = nt * 16 + c15;
                float h = fmaxf(acc[mt][nt][r] + bbv[nt], 0.f);
                my[edge * 64 + ((ch + edge) & 63)] = __float_as_int(h);
            }

    // segmented aggregation (edges dst-sorted); lane = channel
    int dprev = __builtin_amdgcn_readfirstlane(d);
    float run = 0.f;
#pragma unroll
    for (int i = 0; i < 64; ++i) {
        float v = __int_as_float(my[i * 64 + ((lane + i) & 63)]);
        int dd = __builtin_amdgcn_readlane(d, i);
        if (dd != dprev) {
            atomicMax(&agg[(size_t)dprev * 64 + lane], __float_as_uint(run));
            run = 0.f; dprev = dd;
        }
        run = fmaxf(run, v);
    }
    atomicMax(&agg[(size_t)dprev * 64 + lane], __float_as_uint(run));
}

// out[i] = h2[i,:] @ Wl + bl
__global__ __launch_bounds__(256) void final_linear(
    const float* __restrict__ h2, const float* __restrict__ Wl,
    const float* __restrict__ bl, float* __restrict__ out)
{
    int i = blockIdx.x * 256 + threadIdx.x;
    if (i >= NN) return;
    const float4* row = (const float4*)(h2 + (size_t)i * 64);
    float acc = bl[0];
#pragma unroll
    for (int q = 0; q < 16; ++q) {
        float4 v = row[q];
        acc = fmaf(v.x, Wl[q * 4 + 0], acc);
        acc = fmaf(v.y, Wl[q * 4 + 1], acc);
        acc = fmaf(v.z, Wl[q * 4 + 2], acc);
        acc = fmaf(v.w, Wl[q * 4 + 3], acc);
    }
    out[i] = acc;
}

extern "C" void kernel_launch(void* const* d_in, const int* in_sizes, int n_in,
                              void* d_out, int out_size, void* d_ws, size_t ws_size,
                              hipStream_t stream)
{
    const float* x   = (const float*)d_in[0];
    const int*   ei  = (const int*)d_in[1];
    const float* W1a = (const float*)d_in[2];
    const float* b1a = (const float*)d_in[3];
    const float* W1b = (const float*)d_in[4];
    const float* b1b = (const float*)d_in[5];
    const float* W2a = (const float*)d_in[6];
    const float* b2a = (const float*)d_in[7];
    const float* W2b = (const float*)d_in[8];
    const float* b2b = (const float*)d_in[9];
    const float* Wl  = (const float*)d_in[10];
    const float* bl  = (const float*)d_in[11];

    const int* src = ei;
    const int* dst = ei + NE;

    float* ws = (float*)d_ws;
    float* A    = ws + A_OFF;
    float* B    = ws + B_OFF;
    unsigned int* AGG = (unsigned int*)(ws + AGG_OFF);
    int* ib = (int*)(ws + INT_OFF);
    int* counts   = ib + CNT_I;
    int* cursor   = ib + CUR_I;
    int* partials = ib + PART_I;
    int* base     = ib + BASE_I;
    int* ssrc     = ib + SSRC_I;
    int* sdst     = ib + SDST_I;

    hipMemsetAsync(counts, 0, 100352 * sizeof(int), stream);
    hipMemsetAsync(AGG, 0, (size_t)N64 * sizeof(float), stream);

    prep_weights<<<16, 256, 0, stream>>>(W1a, W2a, ws);
    prep_frags<<<8, 256, 0, stream>>>(W1b, W2b, ws);
    node_mlp1<<<391, 256, 0, stream>>>(x, ws + W1D_OFF, ws + W1S_OFF, b1a, A, B);

    k_hist   <<<NE / 256, 256, 0, stream>>>(dst, counts);
    k_scanA  <<<392, 256, 0, stream>>>(counts, cursor, partials);
    k_scanB  <<<1, 512, 0, stream>>>(partials, base);
    k_scatter<<<NE / 256, 256, 0, stream>>>(src, dst, cursor, base, ssrc, sdst);

    edge_layer_mfma<<<NE / 256, 256, 0, stream>>>(A, B, ssrc, sdst,
                                                  (const int*)(ws + WB1F_OFF), b1b, AGG);

    node_mlp2<<<391, 256, 0, stream>>>((float*)AGG, ws + W2D_OFF, ws + W2S_OFF, b2a, A, B);

    edge_layer_mfma<<<NE / 256, 256, 0, stream>>>(A, B, ssrc, sdst,
                                                  (const int*)(ws + WB2F_OFF), b2b, AGG);

    final_linear<<<391, 256, 0, stream>>>((const float*)AGG, Wl, bl, (float*)d_out);
}

// Round 4
// 607.514 us; speedup vs baseline: 3.1082x; 1.1112x over previous
//
#include <hip/hip_runtime.h>

#define NN 100000
#define NE 1600000
#define N64 (NN * 64)

typedef __attribute__((ext_vector_type(8))) short bf16x8;
typedef __attribute__((ext_vector_type(4))) float fx4;

// ---- workspace layout (dword offsets) ----
#define W1D_OFF 0
#define W1S_OFF 448
#define W2D_OFF 896
#define W2S_OFF 4992
#define WB1F_OFF 9216                 // packed Wb frags layer1: 4096 dwords
#define WB2F_OFF 13312                // layer2: 4096 dwords
#define A_OFF   32768
#define B_OFF   (A_OFF + N64)
#define AGG_OFF (B_OFF + N64)
#define INT_OFF (AGG_OFF + N64)
#define CNT_I   0                     // counts   [100352]
#define CUR_I   100352                // cursor   [100352]
#define PART_I  200704                // partials [512]
#define BASE_I  201216                // base     [512]
#define SEDG_I  201728                // sorted int2{src,dst} [NE]

union FragU { int i[4]; bf16x8 f; };

// One prep kernel: zero histogram, precombine Wa weights, build Wb MFMA frags.
// grid 392x256 covers counts[100352]; first blocks do the small weight work.
__global__ __launch_bounds__(256) void prep_all(
    const float* __restrict__ W1a, const float* __restrict__ W1b,
    const float* __restrict__ W2a, const float* __restrict__ W2b,
    float* __restrict__ ws, int* __restrict__ counts)
{
    int t = blockIdx.x * 256 + threadIdx.x;
    if (t < 100352) counts[t] = 0;
    if (t < 448) {
        float top = W1a[t], bot = W1a[448 + t];
        ws[W1D_OFF + t] = top - bot;
        ws[W1S_OFF + t] = bot;
    }
    if (t < 4096) {
        float top = W2a[t], bot = W2a[4096 + t];
        ws[W2D_OFF + t] = top - bot;
        ws[W2S_OFF + t] = bot;
    }
    // Wb fragments (hi/lo truncation split), layout:
    // int4 index r = mat*512 + ks*256 + nt*64 + lane; lane gives k=(lane>>4)*8+j+32ks,
    // n=(lane&15)+16nt, j packed 2 per dword.
    if (t < 2048) {
        int layer = t >> 10;
        int r = t & 1023;
        int ks = (r >> 8) & 1, nt = (r >> 6) & 3, lane = r & 63, mat = r >> 9;
        const float* Wb = layer ? W2b : W1b;
        int* out = (int*)(ws + (layer ? WB2F_OFF : WB1F_OFF));
        int quad = lane >> 4, c = lane & 15, n = nt * 16 + c;
        unsigned dw[4];
#pragma unroll
        for (int d = 0; d < 4; ++d) {
            unsigned v[2];
#pragma unroll
            for (int e = 0; e < 2; ++e) {
                int k = quad * 8 + d * 2 + e + 32 * ks;
                float w = Wb[k * 64 + n];
                unsigned u = __float_as_uint(w);
                if (mat == 0) v[e] = u >> 16;                        // hi = trunc
                else {
                    float lo = w - __uint_as_float(u & 0xFFFF0000u); // exact residual
                    v[e] = __float_as_uint(lo) >> 16;
                }
            }
            dw[d] = (v[1] << 16) | v[0];
        }
        ((int4*)out)[r] = make_int4((int)dw[0], (int)dw[1], (int)dw[2], (int)dw[3]);
    }
}

// A[i] = x_i @ Wd + ba ; B[i] = x_i @ Ws   (7-ch input); also zero AGG row.
__global__ __launch_bounds__(256) void node_mlp1(
    const float* __restrict__ x, const float* __restrict__ Wd,
    const float* __restrict__ Ws, const float* __restrict__ ba,
    float* __restrict__ A, float* __restrict__ Bv, float* __restrict__ agg)
{
    int i = blockIdx.x * 256 + threadIdx.x;
    if (i >= NN) return;
    float xv[7];
#pragma unroll
    for (int k = 0; k < 7; ++k) xv[k] = x[i * 7 + k];
    float4* pa = (float4*)(A + (size_t)i * 64);
    float4* pb = (float4*)(Bv + (size_t)i * 64);
    float4* pz = (float4*)(agg + (size_t)i * 64);
#pragma unroll
    for (int q = 0; q < 16; ++q) pz[q] = make_float4(0.f, 0.f, 0.f, 0.f);
#pragma unroll
    for (int half = 0; half < 2; ++half) {
        float acc[32];
#pragma unroll
        for (int c = 0; c < 32; ++c) acc[c] = ba[half * 32 + c];
#pragma unroll
        for (int k = 0; k < 7; ++k)
#pragma unroll
            for (int c = 0; c < 32; ++c)
                acc[c] = fmaf(xv[k], Wd[k * 64 + half * 32 + c], acc[c]);
#pragma unroll
        for (int q = 0; q < 8; ++q)
            pa[half * 8 + q] = make_float4(acc[q*4], acc[q*4+1], acc[q*4+2], acc[q*4+3]);
#pragma unroll
        for (int c = 0; c < 32; ++c) acc[c] = 0.0f;
#pragma unroll
        for (int k = 0; k < 7; ++k)
#pragma unroll
            for (int c = 0; c < 32; ++c)
                acc[c] = fmaf(xv[k], Ws[k * 64 + half * 32 + c], acc[c]);
#pragma unroll
        for (int q = 0; q < 8; ++q)
            pb[half * 8 + q] = make_float4(acc[q*4], acc[q*4+1], acc[q*4+2], acc[q*4+3]);
    }
}

// A[i] = g_i @ Wd + ba2 ; B[i] = g_i @ Ws ; then zero g row (re-arm AGG for layer 2)
__global__ __launch_bounds__(256) void node_mlp2(
    float* __restrict__ g, const float* __restrict__ Wd,
    const float* __restrict__ Ws, const float* __restrict__ ba2,
    float* __restrict__ A, float* __restrict__ Bv)
{
    int i = blockIdx.x * 256 + threadIdx.x;
    if (i >= NN) return;
    float gv[64];
    float4* pg = (float4*)(g + (size_t)i * 64);
#pragma unroll
    for (int q = 0; q < 16; ++q) {
        float4 v = pg[q];
        gv[q*4+0] = v.x; gv[q*4+1] = v.y; gv[q*4+2] = v.z; gv[q*4+3] = v.w;
    }
#pragma unroll
    for (int q = 0; q < 16; ++q) pg[q] = make_float4(0.f, 0.f, 0.f, 0.f);
    float4* pa = (float4*)(A + (size_t)i * 64);
    float4* pb = (float4*)(Bv + (size_t)i * 64);
#pragma unroll
    for (int half = 0; half < 2; ++half) {
        float acc[32];
#pragma unroll
        for (int c = 0; c < 32; ++c) acc[c] = ba2[half * 32 + c];
#pragma unroll
        for (int j = 0; j < 64; ++j)
#pragma unroll
            for (int c = 0; c < 32; ++c)
                acc[c] = fmaf(gv[j], Wd[j * 64 + half * 32 + c], acc[c]);
#pragma unroll
        for (int q = 0; q < 8; ++q)
            pa[half * 8 + q] = make_float4(acc[q*4], acc[q*4+1], acc[q*4+2], acc[q*4+3]);
#pragma unroll
        for (int c = 0; c < 32; ++c) acc[c] = 0.0f;
#pragma unroll
        for (int j = 0; j < 64; ++j)
#pragma unroll
            for (int c = 0; c < 32; ++c)
                acc[c] = fmaf(gv[j], Ws[j * 64 + half * 32 + c], acc[c]);
#pragma unroll
        for (int q = 0; q < 8; ++q)
            pb[half * 8 + q] = make_float4(acc[q*4], acc[q*4+1], acc[q*4+2], acc[q*4+3]);
    }
}

// ---- counting sort of edges by dst ----
__global__ __launch_bounds__(256) void k_hist(const int* __restrict__ dst, int* __restrict__ counts)
{
    int e = blockIdx.x * 256 + threadIdx.x;
    if (e < NE) atomicAdd(&counts[dst[e]], 1);
}

__global__ __launch_bounds__(256) void k_scanA(
    const int* __restrict__ counts, int* __restrict__ cursor, int* __restrict__ partials)
{
    __shared__ int sh[256];
    int t = threadIdx.x, i = blockIdx.x * 256 + t;
    int c = counts[i];
    sh[t] = c; __syncthreads();
#pragma unroll
    for (int off = 1; off < 256; off <<= 1) {
        int v = (t >= off) ? sh[t - off] : 0;
        __syncthreads();
        sh[t] += v;
        __syncthreads();
    }
    cursor[i] = sh[t] - c;
    if (t == 255) partials[blockIdx.x] = sh[t];
}

__global__ __launch_bounds__(512) void k_scanB(const int* __restrict__ partials, int* __restrict__ base)
{
    __shared__ int sh[512];
    int t = threadIdx.x;
    int c = (t < 392) ? partials[t] : 0;
    sh[t] = c; __syncthreads();
#pragma unroll
    for (int off = 1; off < 512; off <<= 1) {
        int v = (t >= off) ? sh[t - off] : 0;
        __syncthreads();
        sh[t] += v;
        __syncthreads();
    }
    if (t < 392) base[t] = sh[t] - c;
}

__global__ __launch_bounds__(256) void k_scatter(
    const int* __restrict__ src, const int* __restrict__ dst,
    int* __restrict__ cursor, const int* __restrict__ base,
    int2* __restrict__ sedge)
{
    int e = blockIdx.x * 256 + threadIdx.x;
    if (e >= NE) return;
    int dd = dst[e];
    int pos = atomicAdd(&cursor[dd], 1) + base[dd >> 8];
    sedge[pos] = make_int2(src[e], dd);
}

// MFMA edge layer, direct per-lane fragment gather (no staging LDS).
// Wave = 64 edges. Lane supplies A-frag rows m=c15 (edge 16mt+c15), k=32ks+quad*8..+8:
// gathers 8 floats of A[dst]/B[src] directly, t=relu(a+b), bf16 hi/lo split in-register.
// 3-pass split MFMA; epilogue chunked 16 edges (4KB LDS), segmented atomicMax with carry.
__global__ __launch_bounds__(256, 3) void edge_layer_mfma(
    const float* __restrict__ A, const float* __restrict__ Bv,
    const int2* __restrict__ se,
    const int* __restrict__ wbf, const float* __restrict__ bb,
    unsigned int* __restrict__ agg)
{
    __shared__ int lds[4][1152];           // per wave: 128 idx dw + 1024 chunk dw
    const int tid = threadIdx.x;
    const int wv = tid >> 6, lane = tid & 63;
    int* idxb = lds[wv];
    int* chunk = lds[wv] + 128;
    const int quad = lane >> 4, c15 = lane & 15;
    const int base = (blockIdx.x * 4 + wv) * 64;

    int2 ed = se[base + lane];
    ((int2*)idxb)[lane] = ed;              // ds_write_b64; same-wave, no barrier
    const int d_all = ed.y;

    fx4 acc[4][4];
#pragma unroll
    for (int mt = 0; mt < 4; ++mt)
#pragma unroll
        for (int nt = 0; nt < 4; ++nt)
            acc[mt][nt] = (fx4){0.f, 0.f, 0.f, 0.f};

    // broadcast edge indices for this lane's fragment rows (4 mt tiles)
    int2 es[4];
#pragma unroll
    for (int mt = 0; mt < 4; ++mt)
        es[mt] = ((const int2*)idxb)[mt * 16 + c15];   // same-address broadcast per quad

#pragma unroll
    for (int ks = 0; ks < 2; ++ks) {
        // weight fragments for this ks (L1-hot): mat={hi,lo} x nt
        bf16x8 wh[4], wl[4];
#pragma unroll
        for (int nt = 0; nt < 4; ++nt) {
            int4 v = ((const int4*)wbf)[(ks * 4 + nt) * 64 + lane];          // mat=0
            FragU u; u.i[0] = v.x; u.i[1] = v.y; u.i[2] = v.z; u.i[3] = v.w;
            wh[nt] = u.f;
            int4 v2 = ((const int4*)wbf)[((2 + ks) * 4 + nt) * 64 + lane];   // mat=1
            FragU u2; u2.i[0] = v2.x; u2.i[1] = v2.y; u2.i[2] = v2.z; u2.i[3] = v2.w;
            wl[nt] = u2.f;
        }
#pragma unroll
        for (int mt = 0; mt < 4; ++mt) {
            const float4* pa = (const float4*)(A + (size_t)es[mt].y * 64 + ks * 32 + quad * 8);
            const float4* pb = (const float4*)(Bv + (size_t)es[mt].x * 64 + ks * 32 + quad * 8);
            float4 a0 = pa[0], a1 = pa[1];
            float4 b0 = pb[0], b1 = pb[1];
            float t[8];
            t[0] = fmaxf(a0.x + b0.x, 0.f); t[1] = fmaxf(a0.y + b0.y, 0.f);
            t[2] = fmaxf(a0.z + b0.z, 0.f); t[3] = fmaxf(a0.w + b0.w, 0.f);
            t[4] = fmaxf(a1.x + b1.x, 0.f); t[5] = fmaxf(a1.y + b1.y, 0.f);
            t[6] = fmaxf(a1.z + b1.z, 0.f); t[7] = fmaxf(a1.w + b1.w, 0.f);
            FragU uh, ul;
#pragma unroll
            for (int d2 = 0; d2 < 4; ++d2) {
                unsigned u0 = __float_as_uint(t[2 * d2]);
                unsigned u1 = __float_as_uint(t[2 * d2 + 1]);
                uh.i[d2] = (int)((u1 & 0xFFFF0000u) | (u0 >> 16));
                float l0 = t[2 * d2]     - __uint_as_float(u0 & 0xFFFF0000u);
                float l1 = t[2 * d2 + 1] - __uint_as_float(u1 & 0xFFFF0000u);
                ul.i[d2] = (int)((__float_as_uint(l1) & 0xFFFF0000u) |
                                 (__float_as_uint(l0) >> 16));
            }
            bf16x8 fah = uh.f, fal = ul.f;
#pragma unroll
            for (int nt = 0; nt < 4; ++nt) {
                acc[mt][nt] = __builtin_amdgcn_mfma_f32_16x16x32_bf16(fah, wh[nt], acc[mt][nt], 0, 0, 0);
                acc[mt][nt] = __builtin_amdgcn_mfma_f32_16x16x32_bf16(fah, wl[nt], acc[mt][nt], 0, 0, 0);
                acc[mt][nt] = __builtin_amdgcn_mfma_f32_16x16x32_bf16(fal, wh[nt], acc[mt][nt], 0, 0, 0);
            }
        }
    }

    // epilogue: bias+relu, 16-edge LDS chunks (2-way-max bank swizzle), segmented max
    float bbv[4];
#pragma unroll
    for (int nt = 0; nt < 4; ++nt) bbv[nt] = bb[nt * 16 + c15];

    int dprev = __builtin_amdgcn_readlane(d_all, 0);
    float run = 0.f;
#pragma unroll
    for (int mt = 0; mt < 4; ++mt) {
#pragma unroll
        for (int nt = 0; nt < 4; ++nt)
#pragma unroll
            for (int r = 0; r < 4; ++r) {
                int ee = mt * 16 + quad * 4 + r;
                int ch = nt * 16 + c15;
                float h = fmaxf(acc[mt][nt][r] + bbv[nt], 0.f);
                chunk[(ee & 15) * 64 + ((ch + 4 * ee) & 63)] = __float_as_int(h);
            }
#pragma unroll
        for (int i = 0; i < 16; ++i) {
            int ee = mt * 16 + i;
            float v = __int_as_float(chunk[i * 64 + ((lane + 4 * ee) & 63)]);
            int dd = __builtin_amdgcn_readlane(d_all, ee);
            if (dd != dprev) {
                atomicMax(&agg[(size_t)dprev * 64 + lane], __float_as_uint(run));
                run = 0.f; dprev = dd;
            }
            run = fmaxf(run, v);
        }
    }
    atomicMax(&agg[(size_t)dprev * 64 + lane], __float_as_uint(run));
}

// out[i] = h2[i,:] @ Wl + bl
__global__ __launch_bounds__(256) void final_linear(
    const float* __restrict__ h2, const float* __restrict__ Wl,
    const float* __restrict__ bl, float* __restrict__ out)
{
    int i = blockIdx.x * 256 + threadIdx.x;
    if (i >= NN) return;
    const float4* row = (const float4*)(h2 + (size_t)i * 64);
    float acc = bl[0];
#pragma unroll
    for (int q = 0; q < 16; ++q) {
        float4 v = row[q];
        acc = fmaf(v.x, Wl[q * 4 + 0], acc);
        acc = fmaf(v.y, Wl[q * 4 + 1], acc);
        acc = fmaf(v.z, Wl[q * 4 + 2], acc);
        acc = fmaf(v.w, Wl[q * 4 + 3], acc);
    }
    out[i] = acc;
}

extern "C" void kernel_launch(void* const* d_in, const int* in_sizes, int n_in,
                              void* d_out, int out_size, void* d_ws, size_t ws_size,
                              hipStream_t stream)
{
    const float* x   = (const float*)d_in[0];
    const int*   ei  = (const int*)d_in[1];
    const float* W1a = (const float*)d_in[2];
    const float* b1a = (const float*)d_in[3];
    const float* W1b = (const float*)d_in[4];
    const float* b1b = (const float*)d_in[5];
    const float* W2a = (const float*)d_in[6];
    const float* b2a = (const float*)d_in[7];
    const float* W2b = (const float*)d_in[8];
    const float* b2b = (const float*)d_in[9];
    const float* Wl  = (const float*)d_in[10];
    const float* bl  = (const float*)d_in[11];

    const int* src = ei;
    const int* dst = ei + NE;

    float* ws = (float*)d_ws;
    float* A    = ws + A_OFF;
    float* B    = ws + B_OFF;
    unsigned int* AGG = (unsigned int*)(ws + AGG_OFF);
    int* ib = (int*)(ws + INT_OFF);
    int* counts   = ib + CNT_I;
    int* cursor   = ib + CUR_I;
    int* partials = ib + PART_I;
    int* base     = ib + BASE_I;
    int2* sedge   = (int2*)(ib + SEDG_I);

    prep_all<<<392, 256, 0, stream>>>(W1a, W1b, W2a, W2b, ws, counts);
    node_mlp1<<<391, 256, 0, stream>>>(x, ws + W1D_OFF, ws + W1S_OFF, b1a, A, B, (float*)AGG);

    k_hist   <<<NE / 256, 256, 0, stream>>>(dst, counts);
    k_scanA  <<<392, 256, 0, stream>>>(counts, cursor, partials);
    k_scanB  <<<1, 512, 0, stream>>>(partials, base);
    k_scatter<<<NE / 256, 256, 0, stream>>>(src, dst, cursor, base, sedge);

    edge_layer_mfma<<<NE / 256, 256, 0, stream>>>(A, B, sedge,
                                                  (const int*)(ws + WB1F_OFF), b1b, AGG);

    node_mlp2<<<391, 256, 0, stream>>>((float*)AGG, ws + W2D_OFF, ws + W2S_OFF, b2a, A, B);

    edge_layer_mfma<<<NE / 256, 256, 0, stream>>>(A, B, sedge,
                                                  (const int*)(ws + WB2F_OFF), b2b, AGG);

    final_linear<<<391, 256, 0, stream>>>((const float*)AGG, Wl, bl, (float*)d_out);
}